// Round 1
// baseline (153.598 us; speedup 1.0000x reference)
//
#include <hip/hip_runtime.h>

// RandomPick: out[b,h,w,c] = (vector[0,c] >= -5) ? ip1[b,h,w,c] : ip2[b,h,w,c]
// B=32,H=64,W=64,C=128 fp32. Memory-bound. C is innermost/contiguous, so each
// float4 spans channels 4g..4g+3 (g in [0,32)). Per-group 4-bit mask code:
//   code==15 -> all from ip1 (common case: P(mask bit false) ~ 3e-7)
//   code==0  -> all from ip2
//   else     -> mixed, read both and select per lane-element.
// Common case reads only ONE input: 64 MiB read + 64 MiB write ~= 21 us roofline.

#define BLOCK 256

__global__ __launch_bounds__(BLOCK) void randompick_kernel(
    const float4* __restrict__ ip1,
    const float4* __restrict__ ip2,
    const float*  __restrict__ vec,   // [B, C]; only row 0 used
    float4* __restrict__ out,
    int n4)                            // total float4 elements = B*H*W*C/4
{
    __shared__ int scode[32];          // 4-bit mask code per 4-channel group

    const int tid = threadIdx.x;
    if (tid < 32) {
        // vector[0, 4*tid .. 4*tid+3] — one coalesced float4 per lane, 512 B total.
        const float4 v = reinterpret_cast<const float4*>(vec)[tid];
        int code = (v.x >= -5.0f ? 1 : 0)
                 | (v.y >= -5.0f ? 2 : 0)
                 | (v.z >= -5.0f ? 4 : 0)
                 | (v.w >= -5.0f ? 8 : 0);
        scode[tid] = code;
    }
    __syncthreads();

    const int f = blockIdx.x * BLOCK + tid;
    if (f >= n4) return;

    // 128 channels / 4 per float4 = 32 groups per (b,h,w) row; rows contiguous.
    const int code = scode[f & 31];    // 2 lanes/bank LDS broadcast — conflict-free

    float4 r;
    if (code == 15) {                  // wave-uniform in practice (all-true mask)
        r = ip1[f];
    } else if (code == 0) {
        r = ip2[f];
    } else {                           // mixed group: read both, per-element select
        const float4 a = ip1[f];
        const float4 b = ip2[f];
        r.x = (code & 1) ? a.x : b.x;
        r.y = (code & 2) ? a.y : b.y;
        r.z = (code & 4) ? a.z : b.z;
        r.w = (code & 8) ? a.w : b.w;
    }
    out[f] = r;
}

extern "C" void kernel_launch(void* const* d_in, const int* in_sizes, int n_in,
                              void* d_out, int out_size, void* d_ws, size_t ws_size,
                              hipStream_t stream) {
    const float4* ip1 = (const float4*)d_in[0];
    const float4* ip2 = (const float4*)d_in[1];
    const float*  vec = (const float*)d_in[2];
    float4* out = (float4*)d_out;

    const int n4 = out_size / 4;               // 4,194,304
    const int grid = (n4 + BLOCK - 1) / BLOCK; // 16,384 blocks

    randompick_kernel<<<grid, BLOCK, 0, stream>>>(ip1, ip2, vec, out, n4);
}

// Round 2
// 150.047 us; speedup vs baseline: 1.0237x; 1.0237x over previous
//
#include <hip/hip_runtime.h>

// RandomPick: out[b,h,w,c] = (vector[0,c] >= -5) ? ip1[b,h,w,c] : ip2[b,h,w,c]
// B=32,H=64,W=64,C=128 fp32, C innermost. Each float4 spans channels 4g..4g+3.
// Mask is per-channel; with N(0,1) inputs P(bit false) ~ 3e-7, so the common
// case reads ONLY ip1: 64 MiB read + 64 MiB write ~= 21 us at 6.3 TB/s.
// R2 changes vs R1: drop LDS+__syncthreads (per-thread L1-cached vec load
// instead), nontemporal loads/stores on the 64 MiB streams (no reuse -> don't
// let the write stream churn L2).

#define BLOCK 256

typedef float vf4 __attribute__((ext_vector_type(4)));  // clang vector type:
// required for __builtin_nontemporal_* (HIP's float4 is a struct).

__global__ __launch_bounds__(BLOCK) void randompick_kernel(
    const vf4* __restrict__ ip1,
    const vf4* __restrict__ ip2,
    const vf4* __restrict__ vec,   // [B,C] fp32 viewed as float4; row 0 = first 32
    vf4* __restrict__ out,
    int n4)
{
    const int f = blockIdx.x * BLOCK + threadIdx.x;
    if (f >= n4) return;

    // Group g = f & 31 (128 channels / 4). 512 B region, L1-resident broadcast.
    const vf4 v = vec[f & 31];
    const int code = (v.x >= -5.0f ? 1 : 0)
                   | (v.y >= -5.0f ? 2 : 0)
                   | (v.z >= -5.0f ? 4 : 0)
                   | (v.w >= -5.0f ? 8 : 0);

    vf4 r;
    if (code == 15) {                 // all-true: common case, single stream read
        r = __builtin_nontemporal_load(&ip1[f]);
    } else if (code == 0) {
        r = __builtin_nontemporal_load(&ip2[f]);
    } else {                          // mixed 4-channel group: read both, select
        const vf4 a = __builtin_nontemporal_load(&ip1[f]);
        const vf4 b = __builtin_nontemporal_load(&ip2[f]);
        r.x = (code & 1) ? a.x : b.x;
        r.y = (code & 2) ? a.y : b.y;
        r.z = (code & 4) ? a.z : b.z;
        r.w = (code & 8) ? a.w : b.w;
    }
    __builtin_nontemporal_store(r, &out[f]);
}

extern "C" void kernel_launch(void* const* d_in, const int* in_sizes, int n_in,
                              void* d_out, int out_size, void* d_ws, size_t ws_size,
                              hipStream_t stream) {
    const vf4* ip1 = (const vf4*)d_in[0];
    const vf4* ip2 = (const vf4*)d_in[1];
    const vf4* vec = (const vf4*)d_in[2];
    vf4* out = (vf4*)d_out;

    const int n4 = out_size / 4;                // 4,194,304 float4s
    const int grid = (n4 + BLOCK - 1) / BLOCK;  // 16,384 blocks

    randompick_kernel<<<grid, BLOCK, 0, stream>>>(ip1, ip2, vec, out, n4);
}